// Round 4
// baseline (123.147 us; speedup 1.0000x reference)
//
#include <hip/hip_runtime.h>

typedef float f32x2  __attribute__((ext_vector_type(2)));
typedef float f32x16 __attribute__((ext_vector_type(16)));

static constexpr int N_DIM = 2048;
static constexpr int XP = 36;   // padded LDS row stride: bank-quad = (9r+q)&7, 2-way min for b128

__device__ __forceinline__ float vmax3(float a, float b, float c) {
    float d;
    asm("v_max3_f32 %0, %1, %2, %3" : "=v"(d) : "v"(a), "v"(b), "v"(c));
    return d;
}

// x row (32 floats, wave-uniform) -> SGPRs. "+s" ties regs so the double-buffer
// stays at 2 buffers (no SGPR blowup from SSA renaming).
__device__ __forceinline__ void sload_row(const float* base, unsigned off,
                                          f32x16& lo, f32x16& hi) {
    asm volatile("s_load_dwordx16 %0, %2, %3\n\t"
                 "s_load_dwordx16 %1, %2, %4"
                 : "+s"(lo), "+s"(hi)
                 : "s"(base), "s"(off), "s"(off + 64u));
}

// dst[js][b][i] = max_{j in segment js} M[i,j]*x[b,j]
// lane = i (64 i per wave, block = 4 waves sharing one 64-row M tile via LDS).
// wave w owns b-rows g*64 + w*16 + r, r=0..15; x rows stream through SGPRs.
template<int JS>
__global__ __launch_bounds__(256, 4)
void trop_main(const float* __restrict__ x, const float* __restrict__ M,
               float* __restrict__ dst, int B)
{
    constexpr int BJ = 32;
    constexpr int JRANGE = N_DIM / JS;
    constexpr int NCH = JRANGE / BJ;

    __shared__ float Msh[2][64][XP];

    const int t    = threadIdx.x;
    const int lane = t & 63;
    const int tw   = __builtin_amdgcn_readfirstlane(t) >> 6;   // wave id, forced SGPR

    const int bid = blockIdx.x;
    const int bpj = (B >> 6) << 5;          // blocks per j-segment = 32 itiles * (B/64) groups
    const int js  = bid / bpj;
    const int rem = bid - js * bpj;
    const int itile = rem & 31;
    const int g     = rem >> 5;

    const int i0   = itile * 64;
    const int jseg = js * JRANGE;

    // wave-uniform x base (rows g*64+tw*16 .. +15, cols jseg..)
    const float* xw = x + (size_t)(g * 64 + tw * 16) * N_DIM + jseg;

    f32x16 xa0 = {}, xa1 = {}, xb0 = {}, xb1 = {};   // SGPR row double-buffer

    float accA[16], accB[16];
#pragma unroll
    for (int r = 0; r < 16; ++r) { accA[r] = -__builtin_inff(); accB[r] = -__builtin_inff(); }

    // ---- stage M chunk 0 (coalesced: 8 threads per 32-float row) ----
#pragma unroll
    for (int p = 0; p < 2; ++p) {
        const int idx = p * 256 + t;
        const int r = idx >> 3, q = idx & 7;
        const float4 v = *(const float4*)(M + (size_t)(i0 + r) * N_DIM + jseg + q * 4);
        *(float4*)&Msh[0][r][q * 4] = v;
    }
    __syncthreads();

#pragma unroll 1
    for (int ch = 0; ch < NCH; ++ch) {
        const int cur = ch & 1;

        // prefetch next M tile to regs (vmcnt wait lands after the 512-VALU body)
        float4 pv0, pv1;
        if (ch + 1 < NCH) {
            const int jn = jseg + (ch + 1) * BJ;
            {
                const int r = t >> 3, q = t & 7;
                pv0 = *(const float4*)(M + (size_t)(i0 + r) * N_DIM + jn + q * 4);
            }
            {
                const int idx = 256 + t;
                const int r = idx >> 3, q = idx & 7;
                pv1 = *(const float4*)(M + (size_t)(i0 + r) * N_DIM + jn + q * 4);
            }
        }

        // this lane's M fragment: row = lane, 32 floats -> 16 vgpr pairs
        f32x2 mp[16];
#pragma unroll
        for (int q = 0; q < 8; ++q) {
            const float4 m4 = *(const float4*)&Msh[cur][lane][q * 4];
            mp[2 * q]     = f32x2{m4.x, m4.y};
            mp[2 * q + 1] = f32x2{m4.z, m4.w};
        }

        const unsigned cb = (unsigned)(ch * BJ * 4);   // chunk byte offset within row
        sload_row(xw, cb, xa0, xa1);                   // row 0 in flight

#pragma unroll
        for (int r = 0; r < 16; ++r) {
            // drain: completes row r's buffer (r=0 also drains the mp ds_reads,
            // so no mixed SMEM/DS partial-count hazard ever exists)
            asm volatile("s_waitcnt lgkmcnt(0)" ::: "memory");
            __builtin_amdgcn_sched_barrier(0);
            if (r + 1 < 16) {                          // issue row r+1 into other buffer
                const unsigned off = cb + (unsigned)((r + 1) * N_DIM * 4);
                if (r & 1) sload_row(xw, off, xa0, xa1);
                else       sload_row(xw, off, xb0, xb1);
            }
            const f32x16& lo = (r & 1) ? xb0 : xa0;
            const f32x16& hi = (r & 1) ? xb1 : xa1;
            float aA = accA[r], aB = accB[r];
#pragma unroll
            for (int k = 0; k < 8; ++k) {
                f32x2 xp = f32x2{lo[2 * k], lo[2 * k + 1]};
                f32x2 p;
                asm("v_pk_mul_f32 %0, %1, %2" : "=v"(p) : "s"(xp), "v"(mp[k]));
                if (k & 1) aB = vmax3(aB, p.x, p.y); else aA = vmax3(aA, p.x, p.y);
            }
#pragma unroll
            for (int k = 0; k < 8; ++k) {
                f32x2 xp = f32x2{hi[2 * k], hi[2 * k + 1]};
                f32x2 p;
                asm("v_pk_mul_f32 %0, %1, %2" : "=v"(p) : "s"(xp), "v"(mp[8 + k]));
                if (k & 1) aB = vmax3(aB, p.x, p.y); else aA = vmax3(aA, p.x, p.y);
            }
            accA[r] = aA; accB[r] = aB;
        }

        if (ch + 1 < NCH) {   // write next tile; one barrier per chunk
            *(float4*)&Msh[cur ^ 1][t >> 3][(t & 7) * 4] = pv0;
            const int idx = 256 + t;
            *(float4*)&Msh[cur ^ 1][idx >> 3][(idx & 7) * 4] = pv1;
            __syncthreads();
        }
    }

    // partial store: i = i0+lane -> coalesced 256B per row
    float* dw = dst + ((size_t)js * B + g * 64 + tw * 16) * N_DIM + i0 + lane;
#pragma unroll
    for (int r = 0; r < 16; ++r)
        dw[(size_t)r * N_DIM] = fmaxf(accA[r], accB[r]);
}

template<int JS>
__global__ __launch_bounds__(256)
void trop_comb(const float* __restrict__ part, float* __restrict__ out, int total4)
{
    const int idx = blockIdx.x * 256 + threadIdx.x;
    if (idx >= total4) return;
    const float4* p = (const float4*)part;
    float4 a = p[idx];
#pragma unroll
    for (int s = 1; s < JS; ++s) {
        const float4 v = p[idx + (size_t)s * total4];
        a.x = fmaxf(a.x, v.x); a.y = fmaxf(a.y, v.y);
        a.z = fmaxf(a.z, v.z); a.w = fmaxf(a.w, v.w);
    }
    ((float4*)out)[idx] = a;
}

extern "C" void kernel_launch(void* const* d_in, const int* in_sizes, int n_in,
                              void* d_out, int out_size, void* d_ws, size_t ws_size,
                              hipStream_t stream)
{
    const float* x = (const float*)d_in[0];
    const float* M = (const float*)d_in[1];
    float* out = (float*)d_out;

    const int B = in_sizes[0] / N_DIM;                  // 256
    const int bpj = (B >> 6) << 5;                      // 128
    const size_t slab = (size_t)B * N_DIM * sizeof(float);
    const int total4 = B * N_DIM / 4;
    const int cblocks = (total4 + 255) / 256;

#define RUN_JS(JSV)                                                                     \
    do {                                                                                \
        hipLaunchKernelGGL(trop_main<JSV>, dim3(bpj * JSV), dim3(256), 0, stream,       \
                           x, M, (float*)d_ws, B);                                      \
        hipLaunchKernelGGL(trop_comb<JSV>, dim3(cblocks), dim3(256), 0, stream,         \
                           (const float*)d_ws, out, total4);                            \
    } while (0)

    if      (ws_size >= 8 * slab) RUN_JS(8);
    else if (ws_size >= 4 * slab) RUN_JS(4);
    else                          RUN_JS(2);
#undef RUN_JS
}

// Round 5
// 112.574 us; speedup vs baseline: 1.0939x; 1.0939x over previous
//
#include <hip/hip_runtime.h>

typedef float f32x2 __attribute__((ext_vector_type(2)));
typedef float f32x4 __attribute__((ext_vector_type(4)));

static constexpr int N_DIM = 2048;
static constexpr int BJ = 32;   // j per staged chunk

__device__ __forceinline__ float vmax3(float a, float b, float c) {
    float d;
    asm("v_max3_f32 %0, %1, %2, %3" : "=v"(d) : "v"(a), "v"(b), "v"(c));
    return d;
}
__device__ __forceinline__ f32x2 pkmul(f32x2 a, f32x2 b) {
    f32x2 d;
    asm("v_pk_mul_f32 %0, %1, %2" : "=v"(d) : "v"(a), "v"(b));
    return d;
}

// dst[js][b][i] = max_{j in segment} M[i,j]*x[b,j]
// Block tile 128b x 128i, thread tile 8b x 8i (acc=64), chunk BJ=32 j's.
// LDS double-buffered; staging global->reg prefetch issued one full chunk
// of compute (2048 VALU) ahead; ONE barrier per chunk.
// Bank plan: x quad ^= (row&7)  -> 16 rows/wave over 8 quads = 2-way (free);
//            M quad ^= (row>>3)&7 -> 4 distinct broadcast quads, conflict-free.
template<int JS>
__global__ __launch_bounds__(256, 2)
void trop_main(const float* __restrict__ x, const float* __restrict__ M,
               float* __restrict__ dst, int B)
{
    constexpr int JRANGE = N_DIM / JS;
    constexpr int NCH = JRANGE / BJ;

    __shared__ f32x4 xsh[2][128][8];
    __shared__ f32x4 msh[2][128][8];

    const int t  = threadIdx.x;
    const int bt = t & 15;      // b-thread  (b rows bt+16u)
    const int it = t >> 4;      // i-thread  (i rows it*8+v)

    const int bid = blockIdx.x;
    const int bpj = (B >> 7) << 4;          // (B/128)*16 = 32
    const int js  = bid / bpj;
    const int rem = bid - js * bpj;
    const int g     = rem >> 4;             // b-group
    const int itile = rem & 15;

    const int b0 = g * 128;
    const int i0 = itile * 128;
    const int jseg = js * JRANGE;

    // ---- staging geometry: pass p covers rows 32p+sr, f4-col sc ----
    const int sr = t >> 3;                  // 0..31
    const int sc = t & 7;                   // 0..7
    const float* xg[4]; const float* mg[4];
    int xq[4], mq[4];
#pragma unroll
    for (int p = 0; p < 4; ++p) {
        const int r = 32 * p + sr;
        xg[p] = x + (size_t)(b0 + r) * N_DIM + jseg + sc * 4;
        mg[p] = M + (size_t)(i0 + r) * N_DIM + jseg + sc * 4;
        xq[p] = sc ^ (r & 7);
        mq[p] = sc ^ ((r >> 3) & 7);
    }

    f32x4 pxv[4], pmv[4];                   // prefetch registers
    auto ldchunk = [&](int ch) {
        const int off = ch * BJ;
#pragma unroll
        for (int p = 0; p < 4; ++p) {
            pxv[p] = *(const f32x4*)(xg[p] + off);
            pmv[p] = *(const f32x4*)(mg[p] + off);
        }
    };
    auto wrchunk = [&](int s) {
#pragma unroll
        for (int p = 0; p < 4; ++p) {
            xsh[s][32 * p + sr][xq[p]] = pxv[p];
            msh[s][32 * p + sr][mq[p]] = pmv[p];
        }
    };

    float acc[8][8];
#pragma unroll
    for (int u = 0; u < 8; ++u)
#pragma unroll
        for (int v = 0; v < 8; ++v)
            acc[u][v] = -__builtin_inff();

    // ---- prologue: chunk 0 staged, chunk 1 in flight ----
    ldchunk(0);
    wrchunk(0);
    if (NCH > 1) ldchunk(1);
    __syncthreads();

#pragma unroll 1
    for (int c = 0; c < NCH; ++c) {
        const int cur = c & 1;

        if (c + 1 < NCH) {
            wrchunk(cur ^ 1);               // pv(c+1) -> other buffer
            if (c + 2 < NCH) ldchunk(c + 2);// issue next loads (hide under compute)
        }

        // ---- compute chunk c from buf[cur]: 8 j-groups of 4 ----
#pragma unroll
        for (int jg = 0; jg < 8; ++jg) {
            f32x4 xv[8], mv[8];
#pragma unroll
            for (int u = 0; u < 8; ++u)
                xv[u] = xsh[cur][bt + 16 * u][jg ^ (bt & 7)];
#pragma unroll
            for (int v = 0; v < 8; ++v)
                mv[v] = msh[cur][it * 8 + v][jg ^ (it & 7)];
#pragma unroll
            for (int v = 0; v < 8; ++v) {
                const f32x2 ml = __builtin_shufflevector(mv[v], mv[v], 0, 1);
                const f32x2 mh = __builtin_shufflevector(mv[v], mv[v], 2, 3);
#pragma unroll
                for (int u = 0; u < 8; ++u) {
                    const f32x2 xl = __builtin_shufflevector(xv[u], xv[u], 0, 1);
                    const f32x2 xh = __builtin_shufflevector(xv[u], xv[u], 2, 3);
                    const f32x2 p0 = pkmul(xl, ml);   // v_pk_mul_f32: 2 products
                    const f32x2 p1 = pkmul(xh, mh);
                    float a = acc[u][v];
                    a = vmax3(a, p0.x, p0.y);          // v_max3_f32: 2 merges
                    a = vmax3(a, p1.x, p1.y);
                    acc[u][v] = a;
                }
            }
        }
        __syncthreads();   // reads of buf[cur] done; writes to buf[cur^1] visible
    }

    // ---- partial store: rows b0+bt+16u, cols i0+it*8.. (2 f4 per row) ----
    float* dw = dst + ((size_t)js * B + b0 + bt) * N_DIM + i0 + it * 8;
#pragma unroll
    for (int u = 0; u < 8; ++u) {
        float* row = dw + (size_t)(16 * u) * N_DIM;
        *(float4*)row       = make_float4(acc[u][0], acc[u][1], acc[u][2], acc[u][3]);
        *(float4*)(row + 4) = make_float4(acc[u][4], acc[u][5], acc[u][6], acc[u][7]);
    }
}

template<int JS>
__global__ __launch_bounds__(256)
void trop_comb(const float* __restrict__ part, float* __restrict__ out, int total4)
{
    const int idx = blockIdx.x * 256 + threadIdx.x;
    if (idx >= total4) return;
    const float4* p = (const float4*)part;
    float4 a = p[idx];
#pragma unroll
    for (int s = 1; s < JS; ++s) {
        const float4 v = p[idx + (size_t)s * total4];
        a.x = fmaxf(a.x, v.x); a.y = fmaxf(a.y, v.y);
        a.z = fmaxf(a.z, v.z); a.w = fmaxf(a.w, v.w);
    }
    ((float4*)out)[idx] = a;
}

extern "C" void kernel_launch(void* const* d_in, const int* in_sizes, int n_in,
                              void* d_out, int out_size, void* d_ws, size_t ws_size,
                              hipStream_t stream)
{
    const float* x = (const float*)d_in[0];
    const float* M = (const float*)d_in[1];
    float* out = (float*)d_out;

    const int B = in_sizes[0] / N_DIM;                  // 256
    const int bpj = (B >> 7) << 4;                      // 32
    const size_t slab = (size_t)B * N_DIM * sizeof(float);
    const int total4 = B * N_DIM / 4;
    const int cblocks = (total4 + 255) / 256;

#define RUN_JS(JSV)                                                                     \
    do {                                                                                \
        hipLaunchKernelGGL(trop_main<JSV>, dim3(bpj * JSV), dim3(256), 0, stream,       \
                           x, M, (float*)d_ws, B);                                      \
        hipLaunchKernelGGL(trop_comb<JSV>, dim3(cblocks), dim3(256), 0, stream,         \
                           (const float*)d_ws, out, total4);                            \
    } while (0)

    if      (ws_size >= 16 * slab) RUN_JS(16);
    else if (ws_size >=  8 * slab) RUN_JS(8);
    else                           RUN_JS(4);
#undef RUN_JS
}